// Round 10
// baseline (267.434 us; speedup 1.0000x reference)
//
#include <hip/hip_runtime.h>
#include <math.h>

// Problem constants (B=1 fixed by reference)
#define NP 9216          // S*S spatial positions
#define DC 256           // channels
#define DN (DC * NP)
#define NTB 36           // 9216 / 256 tiles per dim
#define KCH (NP * 32)    // halves per k-chunk section of a plane

#define FEPS 2.220446049250313e-16f

typedef __attribute__((ext_vector_type(8))) _Float16 half8v;
typedef __attribute__((ext_vector_type(4))) float   float4v;

union HU { _Float16 h; unsigned short u; };
__device__ __forceinline__ unsigned short f2h(float f) { HU x; x.h = (_Float16)f; return x.u; }
__device__ __forceinline__ float h2f(unsigned short s) { HU x; x.u = s; return (float)x.h; }

// Plane layout (k-major): half index off(n,k) = (k>>5)*KCH + n*32 + (k&31)
// Split (same scale): s' = v*inv*2^8; H = fp16(s'), R = fp16(s' - H).
// sim*2^16 = Hx.Hy + Hx.Ry + Rx.Hy (Rx.Ry dropped, ~2^-22 rel).
//
// R10 model: R9's explicit 4-phase regressed (m196's warning: coarse
// phase-split without fine interleave hurts). Back to R8's proven 2-phase
// (156.5us, MfmaUtil 36.8) with the read-minimizing wave geometry:
// 8 waves of 128x64 (m201's shape) -> LDS reads 256->192 per CU per kt
// (-25%) and half the barrier convoys per MFMA. B-block (8 frags) held
// live, rb-outer A transient. Same chain order -> bit-identical.
// R8's kgather finalize-fusion cost +27us non-ksim -> reverted to R7's
// separate kred/kgather/kfin (83us measured).

// ---------------- Kernel 1: fused normalize + fp16 H/R split ----------------
__global__ __launch_bounds__(256) void kprep(
    const float* __restrict__ X, const float* __restrict__ Y,
    float* __restrict__ Xf_out,
    unsigned short* __restrict__ XH, unsigned short* __restrict__ XR,
    unsigned short* __restrict__ YH, unsigned short* __restrict__ YR,
    float* __restrict__ lacc)
{
    __shared__ float tile[64 * 257];   // (n, d) at n*257+d
    __shared__ float psum[4][64];
    __shared__ float invs[64];

    const int t = threadIdx.x;
    const bool isX = (blockIdx.y == 0);
    const float* src = isX ? X : Y;
    unsigned* hT = (unsigned*)(isX ? XH : YH);
    unsigned* rT = (unsigned*)(isX ? XR : YR);
    const int n0 = blockIdx.x * 64;

    if (blockIdx.x == 0 && blockIdx.y == 0 && t == 0) *lacc = 0.0f;

    const int lane = t & 63;
    const int w    = t >> 6;      // wave id -> owns d-range [w*64, w*64+64)

    #pragma unroll 8
    for (int i = 0; i < 64; ++i) {
        int d = w * 64 + i;
        tile[lane * 257 + d] = src[(size_t)d * NP + n0 + lane];
    }
    float s = 0.0f;
    #pragma unroll 8
    for (int i = 0; i < 64; ++i) {
        float v = tile[lane * 257 + w * 64 + i];
        s = fmaf(v, v, s);
    }
    psum[w][lane] = s;
    __syncthreads();
    if (t < 64) {
        float tot = psum[0][t] + psum[1][t] + psum[2][t] + psum[3][t];
        invs[t] = 1.0f / (sqrtf(tot) + FEPS);
    }
    __syncthreads();

    // plane writes, k-major layout; coalesced uints.
    for (int kt = 0; kt < 8; ++kt) {
        #pragma unroll
        for (int p = 0; p < 4; ++p) {
            int idx = p * 256 + t;
            int n = idx >> 4;          // 0..63
            int u = idx & 15;          // uint within chunk (2 halves)
            float inv = invs[n] * 256.0f;
            int d = kt * 32 + 2 * u;
            float s0 = tile[n * 257 + d] * inv;
            float s1 = tile[n * 257 + d + 1] * inv;
            unsigned short h0 = f2h(s0), h1 = f2h(s1);
            unsigned short r0 = f2h(s0 - h2f(h0));
            unsigned short r1 = f2h(s1 - h2f(h1));
            size_t uo = (size_t)kt * (NP * 16) + (size_t)(n0 + n) * 16 + u;
            hT[uo] = (unsigned)h0 | ((unsigned)h1 << 16);
            rT[uo] = (unsigned)r0 | ((unsigned)r1 << 16);
        }
    }

    // exact fp32 Xf output ([d][n], coalesced over n)
    if (isX) {
        const float inv = invs[lane];
        #pragma unroll 8
        for (int i = 0; i < 64; ++i) {
            int d = w * 64 + i;
            Xf_out[(size_t)d * NP + n0 + lane] = tile[lane * 257 + d] * inv;
        }
    }
}

// ---------------- Kernel 2: 256x256 both-in-LDS GEMM, 8 waves of 128x64 ----
__device__ __forceinline__ void glds16(const char* g, char* l)
{
    __builtin_amdgcn_global_load_lds(
        (const __attribute__((address_space(1))) void*)g,
        (__attribute__((address_space(3))) void*)l, 16, 0, 0);
}

__global__ __launch_bounds__(512, 2) void ksim(
    const unsigned short* __restrict__ XH,
    const unsigned short* __restrict__ YH,
    float* __restrict__ pmax, int* __restrict__ pidx)
{
    extern __shared__ char smem[];   // 2 x (A 32K | B 32K) = 128 KB

    const int t = threadIdx.x;
    const size_t PLB = 2 * (size_t)DN;            // H -> R plane byte offset
    const size_t KTB = 2 * (size_t)KCH;           // per-kt chunk byte stride

    // ---- XCD swizzle: 1296 blocks = 8 XCD x 162 (9 cols x 18 rows patch) --
    const int lid = blockIdx.y * NTB + blockIdx.x;
    const int xcd = lid & 7;
    const int r   = lid >> 3;                  // 0..161
    const int ti  = (xcd >> 2) * 18 + r / 9;   // row tile 0..35
    const int tj  = (xcd & 3) * 9 + r % 9;     // col tile 0..35
    const int n0  = ti * 256;                  // X rows
    const int m0  = tj * 256;                  // Y cols

    const int L = t & 63, wid = t >> 6;        // 8 waves: 2M x 4N
    const int wm = wid >> 2, wn = wid & 3;     // wave owns 128 rows x 64 cols
    const int lc = L & 15,  lq = L >> 4;

    // staging: per-thread 2x16B segs per part; source inverse-swizzled
    // (R6-verified involution: XOR bits 4-5 of in-row offset with (row>>1)&3)
    const char* Ab = (const char*)XH + (size_t)n0 * 64;
    const char* Bb = (const char*)YH + (size_t)m0 * 64;
    const int dOf = t * 16;                       // seg 0; seg 1 at +8192
    const int dSw0 = dOf ^ (((dOf >> 7) & 3) << 4);
    const int dSw1 = dSw0 + 8192;                 // bits 7-8 unchanged by +8192

    float4v acc[8][4];
    #pragma unroll
    for (int i = 0; i < 8; ++i)
        #pragma unroll
        for (int j = 0; j < 4; ++j)
            acc[i][j] = (float4v){0.f, 0.f, 0.f, 0.f};

    // ---- prologue: stage kt0 (A-H | A-R | B-H | B-R, 16 KB each) ----
    glds16(Ab + dSw0,       smem + dOf);
    glds16(Ab + dSw1,       smem + dOf + 8192);
    glds16(Ab + PLB + dSw0, smem + 16384 + dOf);
    glds16(Ab + PLB + dSw1, smem + 16384 + dOf + 8192);
    glds16(Bb + dSw0,       smem + 32768 + dOf);
    glds16(Bb + dSw1,       smem + 32768 + dOf + 8192);
    glds16(Bb + PLB + dSw0, smem + 49152 + dOf);
    glds16(Bb + PLB + dSw1, smem + 49152 + dOf + 8192);
    __syncthreads();

    // swizzled fragment read offsets (row-swizzle bits = (lc>>1)&3)
    const int xr  = (lq * 16) ^ (((lc >> 1) & 3) << 4);
    const int axr = (wm * 128 + lc) * 64 + xr;   // A rows: wm*128 + rb*16 + lc
    const int bxr = (wn * 64 + lc) * 64 + xr;    // B rows: wn*64 + cb*16 + lc

    #pragma unroll 1
    for (int kt = 0; kt < 8; ++kt) {
        const char* cur = smem + (kt & 1) * 65536;

        if (kt < 7) {   // stage kt+1 into the other buffer (in flight across MFMAs)
            char* nxt = smem + ((kt + 1) & 1) * 65536;
            const size_t kb = (size_t)(kt + 1) * KTB;
            glds16(Ab + kb + dSw0,       nxt + dOf);
            glds16(Ab + kb + dSw1,       nxt + dOf + 8192);
            glds16(Ab + PLB + kb + dSw0, nxt + 16384 + dOf);
            glds16(Ab + PLB + kb + dSw1, nxt + 16384 + dOf + 8192);
            glds16(Bb + kb + dSw0,       nxt + 32768 + dOf);
            glds16(Bb + kb + dSw1,       nxt + 32768 + dOf + 8192);
            glds16(Bb + PLB + kb + dSw0, nxt + 49152 + dOf);
            glds16(Bb + PLB + kb + dSw1, nxt + 49152 + dOf + 8192);
        }

        // ---- B register block: all 8 B frags live (32 VGPR), read ONCE ----
        half8v Bh[4], Br[4];
        #pragma unroll
        for (int cb = 0; cb < 4; ++cb) {
            Bh[cb] = *(const half8v*)(cur + 32768 + bxr + cb * 1024);
            Br[cb] = *(const half8v*)(cur + 49152 + bxr + cb * 1024);
        }

        // ---- rb-outer MFMA sweep: A read once per rb (16 reads) ----
        __builtin_amdgcn_s_setprio(1);
        #pragma unroll
        for (int rb = 0; rb < 8; ++rb) {
            half8v Ah = *(const half8v*)(cur +         axr + rb * 1024);
            half8v Ar = *(const half8v*)(cur + 16384 + axr + rb * 1024);
            #pragma unroll
            for (int cb = 0; cb < 4; ++cb) {
                float4v v = acc[rb][cb];
                v = __builtin_amdgcn_mfma_f32_16x16x32_f16(Ah, Bh[cb], v, 0, 0, 0);
                v = __builtin_amdgcn_mfma_f32_16x16x32_f16(Ah, Br[cb], v, 0, 0, 0);
                v = __builtin_amdgcn_mfma_f32_16x16x32_f16(Ar, Bh[cb], v, 0, 0, 0);
                acc[rb][cb] = v;
            }
        }
        __builtin_amdgcn_s_setprio(0);

        if (kt < 7) __syncthreads();   // drains next-tile DMA (had full MFMA phase)
    }

    // ---- epilogue: per-row argmax over this wave's 64 cols ----
    // C/D map: col=lane&15, row=lq*4+reg. Scale 2^16 is argmax-invariant.
    float bv[32]; int bc[32];
    #pragma unroll
    for (int s = 0; s < 32; ++s) { bv[s] = -INFINITY; bc[s] = 0; }

    #pragma unroll
    for (int rb = 0; rb < 8; ++rb)
        #pragma unroll
        for (int cb = 0; cb < 4; ++cb) {   // cb ascending = col ascending
            const int col = m0 + wn * 64 + cb * 16 + lc;
            #pragma unroll
            for (int r2 = 0; r2 < 4; ++r2) {
                float v = acc[rb][cb][r2];
                int s = rb * 4 + r2;
                if (v > bv[s]) { bv[s] = v; bc[s] = col; }
            }
        }

    // reduce across the 16 lc lanes (xor<16 stays in the quad-group)
    #pragma unroll
    for (int off = 1; off < 16; off <<= 1) {
        #pragma unroll
        for (int s = 0; s < 32; ++s) {
            float ov = __shfl_xor(bv[s], off, 64);
            int   oi = __shfl_xor(bc[s], off, 64);
            if (ov > bv[s] || (ov == bv[s] && oi < bc[s])) { bv[s] = ov; bc[s] = oi; }
        }
    }

    // combine 4 column waves per row via LDS table [256][4] (reuses buf0:
    // last read at kt6; kt6-end barrier passed by all waves).
    float* v2s = (float*)smem;
    int*   i2s = (int*)(smem + 4096);

    if (lc == 0) {
        #pragma unroll
        for (int rb = 0; rb < 8; ++rb)
            #pragma unroll
            for (int r2 = 0; r2 < 4; ++r2) {
                int row = wm * 128 + rb * 16 + lq * 4 + r2;
                v2s[row * 4 + wn] = bv[rb * 4 + r2];
                i2s[row * 4 + wn] = bc[rb * 4 + r2];
            }
    }
    __syncthreads();
    if (t < 256) {
        // wn ascending = col ascending: strict '>' keeps first-max semantics.
        float b = v2s[t * 4]; int bi = i2s[t * 4];
        #pragma unroll
        for (int q = 1; q < 4; ++q) {
            float v = v2s[t * 4 + q];
            if (v > b) { b = v; bi = i2s[t * 4 + q]; }
        }
        pmax[(size_t)tj * NP + n0 + t] = b;
        pidx[(size_t)tj * NP + n0 + t] = bi;
    }
}

// ---------------- Kernel 3: reduce 36 tile partials -> nn_idx -------------
__global__ __launch_bounds__(256) void kred(
    const float* __restrict__ pmax, const int* __restrict__ pidx,
    int* __restrict__ nn)
{
    __shared__ float cv[4][64];
    __shared__ int   ci[4][64];

    const int t = threadIdx.x;
    const int n = blockIdx.x * 64 + (t & 63);
    const int p = t >> 6;

    float b = -INFINITY;
    int bi = 0x7fffffff;
    #pragma unroll
    for (int c = p * 9; c < p * 9 + 9; ++c) {
        float v = pmax[(size_t)c * NP + n];
        int  id = pidx[(size_t)c * NP + n];
        if (v > b || (v == b && id < bi)) { b = v; bi = id; }
    }
    cv[p][t & 63] = b;
    ci[p][t & 63] = bi;
    __syncthreads();
    if (t < 64) {
        b = cv[0][t]; bi = ci[0][t];
        #pragma unroll
        for (int q = 1; q < 4; ++q) {
            float v = cv[q][t]; int id = ci[q][t];
            if (v > b || (v == b && id < bi)) { b = v; bi = id; }
        }
        nn[blockIdx.x * 64 + t] = bi;
    }
}

// ---------------- Kernel 4: gather Y_sel + fused MSE loss ----------------
// y = (H + R) * 2^-8 (H/R same scale; error ~2^-22 relative).
__global__ __launch_bounds__(256) void kgather(
    const unsigned short* __restrict__ YH, const unsigned short* __restrict__ YR,
    const int* __restrict__ nn,
    const float* __restrict__ Xf, float* __restrict__ Ysel,
    float* __restrict__ lacc)
{
    __shared__ float tile[64][65];
    __shared__ int   idxs[64];
    __shared__ float wsum[4];

    const int n0 = blockIdx.x * 64;
    const int d0 = blockIdx.y * 64;
    const int tid = threadIdx.x;

    if (tid < 64) idxs[tid] = nn[n0 + tid];
    __syncthreads();

    const int c  = tid & 63;
    const int r0 = tid >> 6;

    #pragma unroll
    for (int s = 0; s < 16; ++s) {
        int r = s * 4 + r0;
        int d = d0 + c;
        size_t off = (size_t)(d >> 5) * KCH + (size_t)idxs[r] * 32 + (d & 31);
        tile[r][c] = (h2f(YH[off]) + h2f(YR[off])) * (1.0f / 256.0f);
    }
    __syncthreads();

    float lsum = 0.0f;
    #pragma unroll
    for (int s = 0; s < 16; ++s) {
        int a = s * 4 + r0;
        int d = d0 + a;
        int n = n0 + c;
        float y = tile[c][a];          // stride-65: conflict-free
        float x = Xf[(size_t)d * NP + n];
        float diff = x - y;
        lsum = fmaf(diff, diff, lsum);
        Ysel[(size_t)d * NP + n] = y;  // coalesced over n
    }

    #pragma unroll
    for (int off = 32; off >= 1; off >>= 1)
        lsum += __shfl_xor(lsum, off, 64);
    if ((tid & 63) == 0) wsum[tid >> 6] = lsum;
    __syncthreads();
    if (tid == 0)
        atomicAdd(lacc, wsum[0] + wsum[1] + wsum[2] + wsum[3]);
}

// ---------------- Kernel 5: finalize loss ----------------
__global__ void kfin(const float* __restrict__ lacc, float* __restrict__ out)
{
    out[0] = lacc[0] * (1.0f / (float)DN);
}

extern "C" void kernel_launch(void* const* d_in, const int* in_sizes, int n_in,
                              void* d_out, int out_size, void* d_ws, size_t ws_size,
                              hipStream_t stream)
{
    const float* X = (const float*)d_in[0];   // X_features [1,256,96,96]
    const float* Y = (const float*)d_in[1];   // Y_features [1,256,96,96]
    // d_in[2], d_in[3] (images) are dead code in the reference — unused.

    float* out = (float*)d_out;
    float* Ysel_out = out + 1;          // output 1: Y_sel [1,D,N]
    float* Xf_out   = out + 1 + DN;     // output 2: Xf   [1,D,N]  (exact fp32)

    // Workspace (~22 MB). XH|XR and YH|YR MUST be contiguous pairs
    // (ksim derives R = H + 2*DN bytes).
    unsigned short* XH = (unsigned short*)d_ws;   // DN halves each
    unsigned short* XR = XH + DN;
    unsigned short* YH = XR + DN;
    unsigned short* YR = YH + DN;
    float* pmax = (float*)(YR + DN);                 // NTB*NP
    int*   pidx = (int*)(pmax + (size_t)NTB * NP);   // NTB*NP
    int*   nn   = pidx + (size_t)NTB * NP;           // NP
    float* lacc = (float*)(nn + NP);                 // 1

    static bool attr_done = false;
    if (!attr_done) {
        hipFuncSetAttribute(reinterpret_cast<const void*>(ksim),
                            hipFuncAttributeMaxDynamicSharedMemorySize, 131072);
        attr_done = true;
    }

    hipLaunchKernelGGL(kprep, dim3(NP / 64, 2), dim3(256), 0, stream,
                       X, Y, Xf_out, XH, XR, YH, YR, lacc);
    hipLaunchKernelGGL(ksim, dim3(NTB, NTB), dim3(512), 131072, stream,
                       XH, YH, pmax, pidx);
    hipLaunchKernelGGL(kred, dim3(NP / 64), dim3(256), 0, stream,
                       pmax, pidx, nn);
    hipLaunchKernelGGL(kgather, dim3(NP / 64, DC / 64), dim3(256), 0, stream,
                       YH, YR, nn, Xf_out, Ysel_out, lacc);
    hipLaunchKernelGGL(kfin, dim3(1), dim3(1), 0, stream, lacc, out);
}

// Round 12
// 244.662 us; speedup vs baseline: 1.0931x; 1.0931x over previous
//
#include <hip/hip_runtime.h>
#include <math.h>

// Problem constants (B=1 fixed by reference)
#define NP 9216          // S*S spatial positions
#define DC 256           // channels
#define DN (DC * NP)
#define NTB 36           // 9216 / 256 tiles per dim
#define KCH (NP * 32)    // halves per k-chunk section of a plane

#define FEPS 2.220446049250313e-16f

typedef __attribute__((ext_vector_type(8))) _Float16 half8v;
typedef __attribute__((ext_vector_type(4))) float   float4v;

union HU { _Float16 h; unsigned short u; };
__device__ __forceinline__ unsigned short f2h(float f) { HU x; x.h = (_Float16)f; return x.u; }
__device__ __forceinline__ float h2f(unsigned short s) { HU x; x.u = s; return (float)x.h; }

// Plane layout (k-major): half index off(n,k) = (k>>5)*KCH + n*32 + (k&31)
// Split (same scale): s' = v*inv*2^8; H = fp16(s'), R = fp16(s' - H).
// sim*2^16 = Hx.Hy + Hx.Ry + Rx.Hy (Rx.Ry dropped, ~2^-22 rel).
//
// R12 == R11 resubmitted (R11 bench was an infra failure: container died
// before any dispatch profile; kernel re-audited, no defect found).
// Wave-count sweep complete: 8w=31%, 12w=34%, 16w=36.8% MfmaUtil ->
// ksim is R8's exact 16-wave kernel (156.5us measured best). Epilogue =
// R7's separate kernels (83us measured best). kred eliminated via
// packed-u64 atomicMax argmax in ksim (key = monotone(float)<<32 | ~col:
// max key == max value, min col on ties == kred semantics, bit-identical).

// ---------------- Kernel 1: fused normalize + fp16 H/R split ----------------
__global__ __launch_bounds__(256) void kprep(
    const float* __restrict__ X, const float* __restrict__ Y,
    float* __restrict__ Xf_out,
    unsigned short* __restrict__ XH, unsigned short* __restrict__ XR,
    unsigned short* __restrict__ YH, unsigned short* __restrict__ YR,
    unsigned long long* __restrict__ nnkey, float* __restrict__ lacc)
{
    __shared__ float tile[64 * 257];   // (n, d) at n*257+d
    __shared__ float psum[4][64];
    __shared__ float invs[64];

    const int t = threadIdx.x;
    const bool isX = (blockIdx.y == 0);
    const float* src = isX ? X : Y;
    unsigned* hT = (unsigned*)(isX ? XH : YH);
    unsigned* rT = (unsigned*)(isX ? XR : YR);
    const int n0 = blockIdx.x * 64;

    if (blockIdx.x == 0 && blockIdx.y == 0 && t == 0) *lacc = 0.0f;
    if (isX && t < 64) nnkey[n0 + t] = 0ull;   // min key: any real value wins

    const int lane = t & 63;
    const int w    = t >> 6;      // wave id -> owns d-range [w*64, w*64+64)

    #pragma unroll 8
    for (int i = 0; i < 64; ++i) {
        int d = w * 64 + i;
        tile[lane * 257 + d] = src[(size_t)d * NP + n0 + lane];
    }
    float s = 0.0f;
    #pragma unroll 8
    for (int i = 0; i < 64; ++i) {
        float v = tile[lane * 257 + w * 64 + i];
        s = fmaf(v, v, s);
    }
    psum[w][lane] = s;
    __syncthreads();
    if (t < 64) {
        float tot = psum[0][t] + psum[1][t] + psum[2][t] + psum[3][t];
        invs[t] = 1.0f / (sqrtf(tot) + FEPS);
    }
    __syncthreads();

    // plane writes, k-major layout; coalesced uints.
    for (int kt = 0; kt < 8; ++kt) {
        #pragma unroll
        for (int p = 0; p < 4; ++p) {
            int idx = p * 256 + t;
            int n = idx >> 4;          // 0..63
            int u = idx & 15;          // uint within chunk (2 halves)
            float inv = invs[n] * 256.0f;
            int d = kt * 32 + 2 * u;
            float s0 = tile[n * 257 + d] * inv;
            float s1 = tile[n * 257 + d + 1] * inv;
            unsigned short h0 = f2h(s0), h1 = f2h(s1);
            unsigned short r0 = f2h(s0 - h2f(h0));
            unsigned short r1 = f2h(s1 - h2f(h1));
            size_t uo = (size_t)kt * (NP * 16) + (size_t)(n0 + n) * 16 + u;
            hT[uo] = (unsigned)h0 | ((unsigned)h1 << 16);
            rT[uo] = (unsigned)r0 | ((unsigned)r1 << 16);
        }
    }

    // exact fp32 Xf output ([d][n], coalesced over n)
    if (isX) {
        const float inv = invs[lane];
        #pragma unroll 8
        for (int i = 0; i < 64; ++i) {
            int d = w * 64 + i;
            Xf_out[(size_t)d * NP + n0 + lane] = tile[lane * 257 + d] * inv;
        }
    }
}

// ---------------- Kernel 2: 256x256 both-in-LDS MFMA GEMM + atomic argmax --
__device__ __forceinline__ void glds16(const char* g, char* l)
{
    __builtin_amdgcn_global_load_lds(
        (const __attribute__((address_space(1))) void*)g,
        (__attribute__((address_space(3))) void*)l, 16, 0, 0);
}

__global__ __launch_bounds__(1024, 4) void ksim(
    const unsigned short* __restrict__ XH,
    const unsigned short* __restrict__ YH,
    unsigned long long* __restrict__ nnkey)
{
    extern __shared__ char smem[];   // 2 x (A 32K | B 32K) = 128 KB

    const int t = threadIdx.x;
    const size_t PLB = 2 * (size_t)DN;            // H -> R plane byte offset
    const size_t KTB = 2 * (size_t)KCH;           // per-kt chunk byte stride

    // ---- XCD swizzle: 1296 blocks = 8 XCD x 162 (9 cols x 18 rows patch) --
    const int lid = blockIdx.y * NTB + blockIdx.x;
    const int xcd = lid & 7;
    const int r   = lid >> 3;                  // 0..161
    const int ti  = (xcd >> 2) * 18 + r / 9;   // row tile 0..35
    const int tj  = (xcd & 3) * 9 + r % 9;     // col tile 0..35
    const int n0  = ti * 256;                  // X rows
    const int m0  = tj * 256;                  // Y cols

    const int L = t & 63, wid = t >> 6;        // 16 waves: 4M x 4N
    const int wm = wid >> 2, wn = wid & 3;
    const int lc = L & 15,  lq = L >> 4;

    // staging: per-thread 16B seg; source inverse-swizzled (R6-verified
    // involution: XOR bits 4-5 of in-row offset with (row>>1)&3)
    const char* Ab = (const char*)XH + (size_t)n0 * 64;
    const char* Bb = (const char*)YH + (size_t)m0 * 64;
    const int dOf = t * 16;
    const int dSw = dOf ^ (((dOf >> 7) & 3) << 4);

    float4v acc[4][4];
    #pragma unroll
    for (int i = 0; i < 4; ++i)
        #pragma unroll
        for (int j = 0; j < 4; ++j)
            acc[i][j] = (float4v){0.f, 0.f, 0.f, 0.f};

    // ---- prologue: stage kt0 ----
    glds16(Ab + dSw,       smem + dOf);
    glds16(Ab + PLB + dSw, smem + 16384 + dOf);
    glds16(Bb + dSw,       smem + 32768 + dOf);
    glds16(Bb + PLB + dSw, smem + 49152 + dOf);
    __syncthreads();

    // swizzled fragment read offsets (row = strip + lc; (row>>1)&3 == (lc>>1)&3)
    const int xr  = (lq * 16) ^ (((lc >> 1) & 3) << 4);
    const int axr = (wm * 64 + lc) * 64 + xr;
    const int bxr = (wn * 64 + lc) * 64 + xr;

    #pragma unroll 1
    for (int kt = 0; kt < 8; ++kt) {
        const char* cur = smem + (kt & 1) * 65536;

        if (kt < 7) {   // stage kt+1 into the other buffer (in flight across MFMAs)
            char* nxt = smem + ((kt + 1) & 1) * 65536;
            const size_t kb = (size_t)(kt + 1) * KTB;
            glds16(Ab + kb + dSw,       nxt + dOf);
            glds16(Ab + PLB + kb + dSw, nxt + 16384 + dOf);
            glds16(Bb + kb + dSw,       nxt + 32768 + dOf);
            glds16(Bb + PLB + kb + dSw, nxt + 49152 + dOf);
        }

        // ---- B register block: all 8 B frags live (32 VGPR), read ONCE ----
        half8v Bh[4], Br[4];
        #pragma unroll
        for (int cb = 0; cb < 4; ++cb) {
            Bh[cb] = *(const half8v*)(cur + 32768 + bxr + cb * 1024);
            Br[cb] = *(const half8v*)(cur + 49152 + bxr + cb * 1024);
        }

        // ---- rb-outer MFMA sweep: A read once per rb (8 reads) ----
        __builtin_amdgcn_s_setprio(1);
        #pragma unroll
        for (int rb = 0; rb < 4; ++rb) {
            half8v Ah = *(const half8v*)(cur +         axr + rb * 1024);
            half8v Ar = *(const half8v*)(cur + 16384 + axr + rb * 1024);
            #pragma unroll
            for (int cb = 0; cb < 4; ++cb) {
                float4v v = acc[rb][cb];
                v = __builtin_amdgcn_mfma_f32_16x16x32_f16(Ah, Bh[cb], v, 0, 0, 0);
                v = __builtin_amdgcn_mfma_f32_16x16x32_f16(Ah, Br[cb], v, 0, 0, 0);
                v = __builtin_amdgcn_mfma_f32_16x16x32_f16(Ar, Bh[cb], v, 0, 0, 0);
                acc[rb][cb] = v;
            }
        }
        __builtin_amdgcn_s_setprio(0);

        if (kt < 7) __syncthreads();   // drains next-tile DMA (had full MFMA phase)
    }

    // ---- epilogue: per-row argmax over this wave's 64 cols ----
    // C/D map: col=lane&15, row=lq*4+reg. Scale 2^16 is argmax-invariant.
    float bv[16]; int bc[16];
    #pragma unroll
    for (int s = 0; s < 16; ++s) { bv[s] = -INFINITY; bc[s] = 0; }

    #pragma unroll
    for (int rb = 0; rb < 4; ++rb)
        #pragma unroll
        for (int cb = 0; cb < 4; ++cb) {   // cb ascending = col ascending
            const int col = m0 + wn * 64 + cb * 16 + lc;
            #pragma unroll
            for (int r2 = 0; r2 < 4; ++r2) {
                float v = acc[rb][cb][r2];
                int s = rb * 4 + r2;
                if (v > bv[s]) { bv[s] = v; bc[s] = col; }
            }
        }

    // reduce across the 16 lc lanes (xor<16 stays in the quad-group)
    #pragma unroll
    for (int off = 1; off < 16; off <<= 1) {
        #pragma unroll
        for (int s = 0; s < 16; ++s) {
            float ov = __shfl_xor(bv[s], off, 64);
            int   oi = __shfl_xor(bc[s], off, 64);
            if (ov > bv[s] || (ov == bv[s] && oi < bc[s])) { bv[s] = ov; bc[s] = oi; }
        }
    }

    // combine 4 column waves per row via LDS table [256][4] (reuses buf0:
    // last read at kt6; every wave passed the kt6-end barrier).
    float* v2s = (float*)smem;
    int*   i2s = (int*)(smem + 4096);

    if (lc == 0) {
        #pragma unroll
        for (int rb = 0; rb < 4; ++rb)
            #pragma unroll
            for (int r2 = 0; r2 < 4; ++r2) {
                int row = wm * 64 + rb * 16 + lq * 4 + r2;
                v2s[row * 4 + wn] = bv[rb * 4 + r2];
                i2s[row * 4 + wn] = bc[rb * 4 + r2];
            }
    }
    __syncthreads();
    if (t < 256) {
        // wn ascending = col ascending: strict '>' keeps first-max semantics.
        float b = v2s[t * 4]; int bi = i2s[t * 4];
        #pragma unroll
        for (int q = 1; q < 4; ++q) {
            float v = v2s[t * 4 + q];
            if (v > b) { b = v; bi = i2s[t * 4 + q]; }
        }
        // packed atomic argmax: key = monotone(b)<<32 | ~col.
        // max key == max value; on equal value, max(~col) == min col ==
        // first-max semantics (identical to the old kred).
        unsigned uv = __float_as_uint(b);
        uv = (uv & 0x80000000u) ? ~uv : (uv | 0x80000000u);
        unsigned long long key =
            ((unsigned long long)uv << 32) | (unsigned)(0xFFFFFFFFu - (unsigned)bi);
        atomicMax(nnkey + n0 + t, key);
    }
}

// ---------------- Kernel 3: gather Y_sel + fused MSE loss ----------------
// y = (H + R) * 2^-8 (H/R same scale; error ~2^-22 relative).
__global__ __launch_bounds__(256) void kgather(
    const unsigned short* __restrict__ YH, const unsigned short* __restrict__ YR,
    const unsigned long long* __restrict__ nnkey,
    const float* __restrict__ Xf, float* __restrict__ Ysel,
    float* __restrict__ lacc)
{
    __shared__ float tile[64][65];
    __shared__ int   idxs[64];
    __shared__ float wsum[4];

    const int n0 = blockIdx.x * 64;
    const int d0 = blockIdx.y * 64;
    const int tid = threadIdx.x;

    if (tid < 64) {
        unsigned long long k = nnkey[n0 + tid];
        idxs[tid] = (int)(0xFFFFFFFFu - (unsigned)(k & 0xFFFFFFFFull));
    }
    __syncthreads();

    const int c  = tid & 63;
    const int r0 = tid >> 6;

    #pragma unroll
    for (int s = 0; s < 16; ++s) {
        int r = s * 4 + r0;
        int d = d0 + c;
        size_t off = (size_t)(d >> 5) * KCH + (size_t)idxs[r] * 32 + (d & 31);
        tile[r][c] = (h2f(YH[off]) + h2f(YR[off])) * (1.0f / 256.0f);
    }
    __syncthreads();

    float lsum = 0.0f;
    #pragma unroll
    for (int s = 0; s < 16; ++s) {
        int a = s * 4 + r0;
        int d = d0 + a;
        int n = n0 + c;
        float y = tile[c][a];          // stride-65: conflict-free
        float x = Xf[(size_t)d * NP + n];
        float diff = x - y;
        lsum = fmaf(diff, diff, lsum);
        Ysel[(size_t)d * NP + n] = y;  // coalesced over n
    }

    #pragma unroll
    for (int off = 32; off >= 1; off >>= 1)
        lsum += __shfl_xor(lsum, off, 64);
    if ((tid & 63) == 0) wsum[tid >> 6] = lsum;
    __syncthreads();
    if (tid == 0)
        atomicAdd(lacc, wsum[0] + wsum[1] + wsum[2] + wsum[3]);
}

// ---------------- Kernel 4: finalize loss ----------------
__global__ void kfin(const float* __restrict__ lacc, float* __restrict__ out)
{
    out[0] = lacc[0] * (1.0f / (float)DN);
}

extern "C" void kernel_launch(void* const* d_in, const int* in_sizes, int n_in,
                              void* d_out, int out_size, void* d_ws, size_t ws_size,
                              hipStream_t stream)
{
    const float* X = (const float*)d_in[0];   // X_features [1,256,96,96]
    const float* Y = (const float*)d_in[1];   // Y_features [1,256,96,96]
    // d_in[2], d_in[3] (images) are dead code in the reference — unused.

    float* out = (float*)d_out;
    float* Ysel_out = out + 1;          // output 1: Y_sel [1,D,N]
    float* Xf_out   = out + 1 + DN;     // output 2: Xf   [1,D,N]  (exact fp32)

    // Workspace (~19 MB). XH|XR and YH|YR MUST be contiguous pairs
    // (ksim derives R = H + 2*DN bytes). nnkey offset is 8*DN bytes (8B-aligned).
    unsigned short* XH = (unsigned short*)d_ws;   // DN halves each
    unsigned short* XR = XH + DN;
    unsigned short* YH = XR + DN;
    unsigned short* YR = YH + DN;
    unsigned long long* nnkey = (unsigned long long*)(YR + DN);   // NP u64
    float* lacc = (float*)(nnkey + NP);                           // 1

    static bool attr_done = false;
    if (!attr_done) {
        hipFuncSetAttribute(reinterpret_cast<const void*>(ksim),
                            hipFuncAttributeMaxDynamicSharedMemorySize, 131072);
        attr_done = true;
    }

    hipLaunchKernelGGL(kprep, dim3(NP / 64, 2), dim3(256), 0, stream,
                       X, Y, Xf_out, XH, XR, YH, YR, nnkey, lacc);
    hipLaunchKernelGGL(ksim, dim3(NTB, NTB), dim3(1024), 131072, stream,
                       XH, YH, nnkey);
    hipLaunchKernelGGL(kgather, dim3(NP / 64, DC / 64), dim3(256), 0, stream,
                       YH, YR, nnkey, Xf_out, Ysel_out, lacc);
    hipLaunchKernelGGL(kfin, dim3(1), dim3(1), 0, stream, lacc, out);
}